// Round 2
// baseline (311.064 us; speedup 1.0000x reference)
//
#include <hip/hip_runtime.h>

// FilterDetection: scores = logits*confs ([4,100000,80] f32),
// boxes = clip(delta2bbox(anchors, regress), 0, 1) ([4,100000,4] f32).
// Memory-bound elementwise; fused single kernel, float4 throughout.

#define FD_B 4
#define FD_N 100000
#define FD_C 80

constexpr int SCORES_ELEMS = FD_B * FD_N * FD_C;   // 32,000,000 floats
constexpr int SCORES_V4    = SCORES_ELEMS / 4;     // 8,000,000 float4
constexpr int NUM_BOXES    = FD_B * FD_N;          // 400,000 (one float4 each)
constexpr int TOTAL_WORK   = SCORES_V4 + NUM_BOXES;

// |log(16/1000)| = 4.135166556742356
#define MAX_RATIO 4.135166556742356f

__global__ __launch_bounds__(256) void fd_kernel(
    const float4* __restrict__ logits,
    const float4* __restrict__ regress,
    const float4* __restrict__ anchors,
    const float4* __restrict__ confs,
    float4* __restrict__ out_scores,
    float4* __restrict__ out_boxes)
{
    int stride = gridDim.x * blockDim.x;
    for (int i = blockIdx.x * blockDim.x + threadIdx.x; i < TOTAL_WORK; i += stride) {
        if (i < SCORES_V4) {
            // scores = logits * confs
            float4 l = logits[i];
            float4 c = confs[i];
            float4 s;
            s.x = l.x * c.x;
            s.y = l.y * c.y;
            s.z = l.z * c.z;
            s.w = l.w * c.w;
            out_scores[i] = s;
        } else {
            // delta2bbox + clip for one (b, n) box
            int bi = i - SCORES_V4;           // [0, B*N)
            int n  = bi % FD_N;               // anchor index (anchors shared over B)
            float4 d = regress[bi];           // dx, dy, dw, dh  (mean=0, std=1)
            float4 a = anchors[n];            // x1, y1, x2, y2

            float px = (a.x + a.z) * 0.5f;
            float py = (a.y + a.w) * 0.5f;
            float pw = a.z - a.x;
            float ph = a.w - a.y;

            float dw = fminf(fmaxf(d.z, -MAX_RATIO), MAX_RATIO);
            float dh = fminf(fmaxf(d.w, -MAX_RATIO), MAX_RATIO);

            float gx = px + pw * d.x;
            float gy = py + ph * d.y;
            float gw = pw * expf(dw);
            float gh = ph * expf(dh);

            float4 o;
            o.x = gx - gw * 0.5f;
            o.y = gy - gh * 0.5f;
            o.z = gx + gw * 0.5f;
            o.w = gy + gh * 0.5f;

            // clip to [0, 1]
            o.x = fminf(fmaxf(o.x, 0.0f), 1.0f);
            o.y = fminf(fmaxf(o.y, 0.0f), 1.0f);
            o.z = fminf(fmaxf(o.z, 0.0f), 1.0f);
            o.w = fminf(fmaxf(o.w, 0.0f), 1.0f);

            out_boxes[bi] = o;
        }
    }
}

extern "C" void kernel_launch(void* const* d_in, const int* in_sizes, int n_in,
                              void* d_out, int out_size, void* d_ws, size_t ws_size,
                              hipStream_t stream) {
    // setup_inputs order: logits, regress, anchors, confs (all float32)
    const float4* logits  = (const float4*)d_in[0];
    const float4* regress = (const float4*)d_in[1];
    const float4* anchors = (const float4*)d_in[2];
    const float4* confs   = (const float4*)d_in[3];

    // d_out: scores [B*N*C] flat, then boxes [B*N*4] flat (tuple concat order)
    float* out = (float*)d_out;
    float4* out_scores = (float4*)out;
    float4* out_boxes  = (float4*)(out + SCORES_ELEMS);  // 128 MB offset, 16B-aligned

    // ~2048 blocks: 524288 threads, ~16 grid-stride iterations each
    const int block = 256;
    const int grid  = 2048;
    fd_kernel<<<grid, block, 0, stream>>>(logits, regress, anchors, confs,
                                          out_scores, out_boxes);
}